// Round 1
// baseline (46.703 us; speedup 1.0000x reference)
//
#include <hip/hip_runtime.h>

// Problem constants (match reference)
#define BB 128
#define CC 5
#define HH 128
#define WW 128
#define HWSZ (HH * WW)              // 16384
#define NCELLS (BB * HH * WW)       // 2,097,152
#define N4 (NCELLS / 4)             // 524,288 float4 cell-groups

__device__ __forceinline__ float4 ld4(const float* p) {
    return *reinterpret_cast<const float4*>(p);
}

__global__ __launch_bounds__(256) void yolo_loss_kernel(
    const float* __restrict__ labela,
    const float* __restrict__ labelb,
    const float* __restrict__ pred_ab,
    const float* __restrict__ pred_ba,
    float* __restrict__ out)
{
    const int i = blockIdx.x * blockDim.x + threadIdx.x;   // float4-group index
    float cell = 0.0f;

    if (i < N4) {
        const int cb = i * 4;                 // base cell index (b*HW + hw)
        const int b  = cb / HWSZ;
        const int hw = cb - b * HWSZ;
        const size_t base = (size_t)b * CC * HWSZ + hw;    // channel-0 offset

        // channel-0 of labela is the objectness mask
        const float4 m4 = ld4(labela + base);

        float sx = 0.f, sy = 0.f, sz = 0.f, sw = 0.f;
        #pragma unroll
        for (int c = 0; c < CC; ++c) {
            const size_t off = base + (size_t)c * HWSZ;
            const float4 la = (c == 0) ? m4 : ld4(labela + off);
            const float4 pa = ld4(pred_ab + off);
            const float4 lb = ld4(labelb + off);
            const float4 pb = ld4(pred_ba + off);
            float d;
            d = la.x - pa.x; sx += d * d;  d = lb.x - pb.x; sx += d * d;
            d = la.y - pa.y; sy += d * d;  d = lb.y - pb.y; sy += d * d;
            d = la.z - pa.z; sz += d * d;  d = lb.z - pb.z; sz += d * d;
            d = la.w - pa.w; sw += d * d;  d = lb.w - pb.w; sw += d * d;
        }
        cell = (m4.x != 0.f ? sx : 0.f)
             + (m4.y != 0.f ? sy : 0.f)
             + (m4.z != 0.f ? sz : 0.f)
             + (m4.w != 0.f ? sw : 0.f);
    }

    // wave(64) shuffle reduction
    #pragma unroll
    for (int off = 32; off > 0; off >>= 1)
        cell += __shfl_down(cell, off, 64);

    __shared__ float wsum[4];                 // 256 threads = 4 waves
    const int lane = threadIdx.x & 63;
    const int wid  = threadIdx.x >> 6;
    if (lane == 0) wsum[wid] = cell;
    __syncthreads();
    if (threadIdx.x == 0) {
        const float t = wsum[0] + wsum[1] + wsum[2] + wsum[3];
        atomicAdd(out, t);
    }
}

extern "C" void kernel_launch(void* const* d_in, const int* in_sizes, int n_in,
                              void* d_out, int out_size, void* d_ws, size_t ws_size,
                              hipStream_t stream) {
    const float* labela  = (const float*)d_in[0];
    const float* labelb  = (const float*)d_in[1];
    const float* pred_ab = (const float*)d_in[2];
    const float* pred_ba = (const float*)d_in[3];
    float* out = (float*)d_out;

    // d_out is poisoned once before timing and never re-poisoned between
    // replays: zero it ourselves every launch (graph-capture safe).
    hipMemsetAsync(out, 0, sizeof(float), stream);

    const int threads = 256;
    const int blocks  = (N4 + threads - 1) / threads;     // 2048
    yolo_loss_kernel<<<blocks, threads, 0, stream>>>(labela, labelb, pred_ab, pred_ba, out);
}

// Round 2
// 45.801 us; speedup vs baseline: 1.0197x; 1.0197x over previous
//
#include <hip/hip_runtime.h>

// Problem constants (match reference)
#define BB 128
#define CC 5
#define HH 128
#define WW 128
#define HWSZ (HH * WW)              // 16384
#define NCELLS (BB * HH * WW)       // 2,097,152
#define N4 (NCELLS / 4)             // 524,288 float4 cell-groups (= 2048 blocks * 256 threads exactly)

__device__ __forceinline__ float4 ld4(const float* p) {
    return *reinterpret_cast<const float4*>(p);
}

__global__ __launch_bounds__(256) void yolo_loss_kernel(
    const float* __restrict__ labela,
    const float* __restrict__ labelb,
    const float* __restrict__ pred_ab,
    const float* __restrict__ pred_ba,
    float* __restrict__ out)
{
    const int i  = blockIdx.x * blockDim.x + threadIdx.x;  // float4-group index (grid exact)
    const int cb = i * 4;                                  // base cell index (b*HW + hw)
    const int b  = cb >> 14;                               // / 16384
    const int hw = cb & (HWSZ - 1);
    const size_t base = (size_t)b * (CC * HWSZ) + hw;      // channel-0 offset

    // ---- load phase: issue all 20 independent float4 loads before any use ----
    float4 la[CC], pa[CC], lb[CC], pb[CC];
    #pragma unroll
    for (int c = 0; c < CC; ++c) la[c] = ld4(labela  + base + (size_t)c * HWSZ);
    #pragma unroll
    for (int c = 0; c < CC; ++c) pa[c] = ld4(pred_ab + base + (size_t)c * HWSZ);
    #pragma unroll
    for (int c = 0; c < CC; ++c) lb[c] = ld4(labelb  + base + (size_t)c * HWSZ);
    #pragma unroll
    for (int c = 0; c < CC; ++c) pb[c] = ld4(pred_ba + base + (size_t)c * HWSZ);

    // ---- compute phase ----
    float sx = 0.f, sy = 0.f, sz = 0.f, sw = 0.f;
    #pragma unroll
    for (int c = 0; c < CC; ++c) {
        float d;
        d = la[c].x - pa[c].x; sx += d * d;  d = lb[c].x - pb[c].x; sx += d * d;
        d = la[c].y - pa[c].y; sy += d * d;  d = lb[c].y - pb[c].y; sy += d * d;
        d = la[c].z - pa[c].z; sz += d * d;  d = lb[c].z - pb[c].z; sz += d * d;
        d = la[c].w - pa[c].w; sw += d * d;  d = lb[c].w - pb[c].w; sw += d * d;
    }
    // la[0] is the objectness mask channel
    float cell = (la[0].x != 0.f ? sx : 0.f)
               + (la[0].y != 0.f ? sy : 0.f)
               + (la[0].z != 0.f ? sz : 0.f)
               + (la[0].w != 0.f ? sw : 0.f);

    // ---- wave(64) shuffle reduction ----
    #pragma unroll
    for (int off = 32; off > 0; off >>= 1)
        cell += __shfl_down(cell, off, 64);

    __shared__ float wsum[4];                 // 256 threads = 4 waves
    const int lane = threadIdx.x & 63;
    const int wid  = threadIdx.x >> 6;
    if (lane == 0) wsum[wid] = cell;
    __syncthreads();
    if (threadIdx.x == 0) {
        const float t = wsum[0] + wsum[1] + wsum[2] + wsum[3];
        atomicAdd(out, t);
    }
}

extern "C" void kernel_launch(void* const* d_in, const int* in_sizes, int n_in,
                              void* d_out, int out_size, void* d_ws, size_t ws_size,
                              hipStream_t stream) {
    const float* labela  = (const float*)d_in[0];
    const float* labelb  = (const float*)d_in[1];
    const float* pred_ab = (const float*)d_in[2];
    const float* pred_ba = (const float*)d_in[3];
    float* out = (float*)d_out;

    // d_out is poisoned once before timing and never re-poisoned between
    // replays: zero it ourselves every launch (graph-capture safe).
    hipMemsetAsync(out, 0, sizeof(float), stream);

    const int threads = 256;
    const int blocks  = N4 / threads;                      // 2048, exact
    yolo_loss_kernel<<<blocks, threads, 0, stream>>>(labela, labelb, pred_ab, pred_ba, out);
}